// Round 11
// baseline (2777.776 us; speedup 1.0000x reference)
//
#include <hip/hip_runtime.h>
#include <stdint.h>

#define Bz 64
#define Tz 512
#define Ez 512
#define Hz 512
#define Lz 12
#define START_ID 10
#define END_ID 11

typedef unsigned int uint32;
typedef unsigned long long uint64;
typedef unsigned short ushort16;
typedef __bf16 bf16x8 __attribute__((ext_vector_type(8)));
typedef float f32x4 __attribute__((ext_vector_type(4)));

__device__ __forceinline__ float bf2f(uint32 u) {
    return __uint_as_float(u << 16);
}
__device__ __forceinline__ ushort16 f2bf(float f) {
    uint32 x = __float_as_uint(f);
    x += 0x7FFFu + ((x >> 16) & 1u);
    return (ushort16)(x >> 16);
}
__device__ __forceinline__ float sigf(float x) {
    return 1.0f / (1.0f + __expf(-x));
}
__device__ __forceinline__ float tanh_fast(float x) {
    return 1.0f - 2.0f / (__expf(2.0f * x) + 1.0f);
}
__device__ __forceinline__ bf16x8 packbf8(float4 a, float4 b) {
    union { ushort16 u[8]; bf16x8 v; } r;
    r.u[0] = f2bf(a.x); r.u[1] = f2bf(a.y); r.u[2] = f2bf(a.z); r.u[3] = f2bf(a.w);
    r.u[4] = f2bf(b.x); r.u[5] = f2bf(b.y); r.u[6] = f2bf(b.z); r.u[7] = f2bf(b.w);
    return r.v;
}

// ---- K0: pack embeds into A-fragment order: emb_p[((bg*512+t)*16+kst)*64 + lane] = 16B ----
// lane l supplies A[row = bg*16 + (l&15)][k = kst*32 + (l>>4)*8 + i], i=0..7
__global__ __launch_bounds__(256) void prepack_kernel(const int* __restrict__ sents,
                                                      const float* __restrict__ emb,
                                                      uint4* __restrict__ emb_p) {
    int c = blockIdx.x * 256 + threadIdx.x;      // 0 .. 2^21-1
    int l   = c & 63;
    int kst = (c >> 6) & 15;
    int t   = (c >> 10) & 511;
    int bg  = c >> 19;
    int b   = (bg << 4) + (l & 15);
    int e0  = (kst << 5) + ((l >> 4) << 3);
    const float* p = emb + (size_t)sents[b * Tz + t] * Ez + e0;
    float4 f0 = *(const float4*)p;
    float4 f1 = *(const float4*)(p + 4);
    uint32 r0 = (uint32)f2bf(f0.x) | ((uint32)f2bf(f0.y) << 16);
    uint32 r1 = (uint32)f2bf(f0.z) | ((uint32)f2bf(f0.w) << 16);
    uint32 r2 = (uint32)f2bf(f1.x) | ((uint32)f2bf(f1.y) << 16);
    uint32 r3 = (uint32)f2bf(f1.z) | ((uint32)f2bf(f1.w) << 16);
    emb_p[c] = make_uint4(r0, r1, r2, r3);
}

// ---- K1: persistent BiLSTM. 128 blocks = 8 groups (2 dir x 4 bgroup of 16 batch) x 16 ugroups(32 units).
// Exchange: TAG-IN-DATA (verified correct & replay-safe in R7/R10) + CALIBRATED ISSUE DELAY:
// all blocks run in lockstep, so the tagged loads are issued only after an s_sleep that
// covers the producer-store -> MALL-visibility window (~1us). First validation round then
// usually succeeds -> single-hop exchange: publish store -> validated bulk load. No flags,
// no acks, no fences. Retry (rare) with s_sleep backoff, guard 4096 (wrong answer, no hang).
__global__ __launch_bounds__(256, 1) void lstm_persist(
    const float* __restrict__ w_ih_f, const float* __restrict__ w_hh_f, const float* __restrict__ b_f,
    const float* __restrict__ w_ih_r, const float* __restrict__ w_hh_r, const float* __restrict__ b_r,
    const uint4* __restrict__ emb_p,
    ushort16* __restrict__ hs,          // [2][64][512][512] bf16
    uint64* __restrict__ h_ppT)         // [2 parity][2 dir][64 batch][256 words] tagged
{
    const int bid = blockIdx.x;
    const int grp = bid & 7;
    const int d   = grp >> 2;
    const int bg  = grp & 3;
    const int ug  = bid >> 3;            // 0..15
    const int tid = threadIdx.x;
    const int w   = tid >> 6;            // wave = gate type
    const int l   = tid & 63;

    __shared__ __align__(16) char h_lds[16384];      // [16 b][512 k] bf16, XOR-swizzled
    __shared__ float gx[2048];                       // [16 b][4 gate][32 u] f32
    __shared__ uint32 h_stage[256];                  // own-block h slice (2 units/word)

    const float* Whh  = d ? w_hh_r : w_hh_f;
    const float* Wih  = d ? w_ih_r : w_ih_f;
    const float* bias = d ? b_r : b_f;
    const int u0 = ug << 5;

    // ---- load B-fragments into registers (two 16-col halves nn=0,1) ----
    bf16x8 Bih[2][16], Bhh[2][16];
    #pragma unroll
    for (int nn = 0; nn < 2; nn++) {
        const int wrow = (w << 9) + u0 + (nn << 4) + (l & 15);
        const int koff = (l >> 4) << 3;
        #pragma unroll
        for (int kst = 0; kst < 16; kst++) {
            const float* p = Wih + (size_t)wrow * Ez + (kst << 5) + koff;
            Bih[nn][kst] = packbf8(*(const float4*)p, *(const float4*)(p + 4));
            const float* q = Whh + (size_t)wrow * Hz + (kst << 5) + koff;
            Bhh[nn][kst] = packbf8(*(const float4*)q, *(const float4*)(q + 4));
        }
    }

    // activation thread mapping: b = tid>>4 (0..15 local), uw = tid&15 -> units 2uw,2uw+1
    const int ab = tid >> 4;
    const int uw = tid & 15;
    const float bi0  = bias[u0 + 2*uw],        bi1  = bias[u0 + 2*uw + 1];
    const float bf0  = bias[512 + u0 + 2*uw],  bf1  = bias[512 + u0 + 2*uw + 1];
    const float bg0  = bias[1024 + u0 + 2*uw], bg1  = bias[1024 + u0 + 2*uw + 1];
    const float bo0  = bias[1536 + u0 + 2*uw], bo1  = bias[1536 + u0 + 2*uw + 1];
    float c0 = 0.0f, c1 = 0.0f;

    const int r16 = tid >> 4, seg = tid & 15;
    const uint4* xbase = emb_p + (((size_t)bg << 9) << 10);

    // preload x fragments for t=0
    uint4 xf[16];
    {
        const uint4* xb = xbase + ((size_t)(d ? (Tz - 1) : 0) << 10) + l;
        #pragma unroll
        for (int kst = 0; kst < 16; kst++) xf[kst] = xb[(size_t)kst << 6];
    }

    for (int t = 0; t < Tz; t++) {
        const int tg = d ? (Tz - 1 - t) : t;

        f32x4 acc0[2], acc1[2];
        #pragma unroll
        for (int i = 0; i < 2; i++) {
            acc0[i] = (f32x4){0.f, 0.f, 0.f, 0.f};
            acc1[i] = (f32x4){0.f, 0.f, 0.f, 0.f};
        }

        // ---- x-GEMM from prefetched registers (no dependence on h(t-1)) ----
        #pragma unroll
        for (int kst = 0; kst < 16; kst++) {
            union { uint4 q; bf16x8 v; } x;
            x.q = xf[kst];
            acc0[kst & 1] = __builtin_amdgcn_mfma_f32_16x16x32_bf16(x.v, Bih[0][kst], acc0[kst & 1], 0, 0, 0);
            acc1[kst & 1] = __builtin_amdgcn_mfma_f32_16x16x32_bf16(x.v, Bih[1][kst], acc1[kst & 1], 0, 0, 0);
        }

        if (t > 0) {
            // ---- calibrated delay: cover producer-store -> MALL-visibility window ----
            __builtin_amdgcn_s_sleep(12);   // ~768 cycles ≈ 0.37 us (wave-level)

            // ---- tagged h(t-1) loads ----
            uint64 hv[16];
            uint64* hp = h_ppT + ((size_t)((((t - 1) & 1) << 1) + d) * 64 + (bg << 4) + r16) * 256 + (seg << 4);
            const uint32 want = (uint32)(t - 1);
            uint32 hd[16];
            if (seg != ug) {
                #pragma unroll
                for (int i = 0; i < 16; i++)
                    hv[i] = __hip_atomic_load(hp + i, __ATOMIC_RELAXED, __HIP_MEMORY_SCOPE_AGENT);
                // validate + batched retry (exec-masked reloads, backoff, guarded)
                int guard = 0;
                for (;;) {
                    bool bad = false;
                    #pragma unroll
                    for (int i = 0; i < 16; i++) {
                        if ((uint32)(hv[i] >> 32) != want) {
                            hv[i] = __hip_atomic_load(hp + i, __ATOMIC_RELAXED, __HIP_MEMORY_SCOPE_AGENT);
                            bad = true;
                        }
                    }
                    if (!bad || ++guard > 4096) break;
                    __builtin_amdgcn_s_sleep(2);
                }
                #pragma unroll
                for (int i = 0; i < 16; i++) hd[i] = (uint32)hv[i];
            } else {
                // own block's slice: forwarded through LDS, no global round trip
                #pragma unroll
                for (int i = 0; i < 16; i++) hd[i] = h_stage[(r16 << 4) + i];
            }

            // ---- fill swizzled h LDS ----
            #pragma unroll
            for (int i = 0; i < 16; i++) {
                const int dj = (seg << 4) + i;          // dword index in row (0..255)
                const int cj = dj >> 2;                 // 16B chunk index
                *(uint32*)(h_lds + (r16 << 10) + (((cj << 4) ^ (r16 << 4))) + ((dj & 3) << 2)) = hd[i];
            }
            __syncthreads();

            // ---- h-GEMM ----
            #pragma unroll
            for (int kst = 0; kst < 16; kst++) {
                bf16x8 a = *(const bf16x8*)(h_lds + ((l & 15) << 10) +
                            (((kst << 6) + ((l >> 4) << 4)) ^ ((l & 15) << 4)));
                acc0[kst & 1] = __builtin_amdgcn_mfma_f32_16x16x32_bf16(a, Bhh[0][kst], acc0[kst & 1], 0, 0, 0);
                acc1[kst & 1] = __builtin_amdgcn_mfma_f32_16x16x32_bf16(a, Bhh[1][kst], acc1[kst & 1], 0, 0, 0);
            }
        }

        f32x4 g0 = acc0[0] + acc0[1];
        f32x4 g1 = acc1[0] + acc1[1];

        // ---- gate exchange: D[row=(l>>4)*4+r][col=l&15] -> gx[b][gate][u] ----
        #pragma unroll
        for (int r = 0; r < 4; r++) {
            const int b = ((l >> 4) << 2) + r;
            gx[(b << 7) + (w << 5) + (l & 15)] = g0[r];
            gx[(b << 7) + (w << 5) + 16 + (l & 15)] = g1[r];
        }
        __syncthreads();

        // ---- activation + tagged publish (2 units per thread) ----
        uint32 hval;
        {
            const int base = (ab << 7) + (uw << 1);
            float gi_0 = gx[base],      gi_1 = gx[base + 1];
            float gf_0 = gx[base + 32], gf_1 = gx[base + 33];
            float gg_0 = gx[base + 64], gg_1 = gx[base + 65];
            float go_0 = gx[base + 96], go_1 = gx[base + 97];
            c0 = sigf(gf_0 + bf0) * c0 + sigf(gi_0 + bi0) * tanh_fast(gg_0 + bg0);
            float hn0 = sigf(go_0 + bo0) * tanh_fast(c0);
            c1 = sigf(gf_1 + bf1) * c1 + sigf(gi_1 + bi1) * tanh_fast(gg_1 + bg1);
            float hn1 = sigf(go_1 + bo1) * tanh_fast(c1);
            hval = (uint32)f2bf(hn0) | ((uint32)f2bf(hn1) << 16);
            const size_t pidx = ((size_t)(((t & 1) << 1) + d) * 64 + (bg << 4) + ab) * 256 + (ug << 4) + uw;
            uint64 pub = ((uint64)(uint32)t << 32) | (uint64)hval;
            __hip_atomic_store(h_ppT + pidx, pub, __ATOMIC_RELAXED, __HIP_MEMORY_SCOPE_AGENT);
            h_stage[(ab << 4) + uw] = hval;
        }

        // ---- off critical path: hs output + x prefetch for t+1 ----
        {
            const size_t hrow = (((size_t)(d << 6) + (bg << 4) + ab) * 512 + tg) * 512 + u0 + (uw << 1);
            *(uint32*)(hs + hrow) = hval;
        }
        if (t < Tz - 1) {
            const int tg2 = d ? (Tz - 2 - t) : (t + 1);
            const uint4* xb = xbase + ((size_t)tg2 << 10) + l;
            #pragma unroll
            for (int kst = 0; kst < 16; kst++) xf[kst] = xb[(size_t)kst << 6];
        }
        __syncthreads();   // protect h_stage/gx (written above) vs next step's reads
    }
}

// ---------------- K3: feats = tanh(concat(hf,hr)) @ fc_w^T + fc_b ----------------
__global__ __launch_bounds__(256) void feat_kernel(const ushort16* __restrict__ hs,
                                                   const float* __restrict__ fc_w,
                                                   const float* __restrict__ fc_b,
                                                   float* __restrict__ feats) {
    const int m = blockIdx.x * 4 + (threadIdx.x >> 6);   // row (b*T+t)
    const int lane = threadIdx.x & 63;

    const ushort16* hf = hs + (size_t)m * Hz + lane * 8;
    const ushort16* hr = hs + (size_t)Bz * Tz * Hz + (size_t)m * Hz + lane * 8;
    uint4 vf = *(const uint4*)hf;
    uint4 vr = *(const uint4*)hr;

    float x[16];
    {
        uint32 w0 = vf.x, w1 = vf.y, w2 = vf.z, w3 = vf.w;
        x[0] = tanh_fast(bf2f(w0 & 0xFFFFu)); x[1] = tanh_fast(bf2f(w0 >> 16));
        x[2] = tanh_fast(bf2f(w1 & 0xFFFFu)); x[3] = tanh_fast(bf2f(w1 >> 16));
        x[4] = tanh_fast(bf2f(w2 & 0xFFFFu)); x[5] = tanh_fast(bf2f(w2 >> 16));
        x[6] = tanh_fast(bf2f(w3 & 0xFFFFu)); x[7] = tanh_fast(bf2f(w3 >> 16));
        w0 = vr.x; w1 = vr.y; w2 = vr.z; w3 = vr.w;
        x[8]  = tanh_fast(bf2f(w0 & 0xFFFFu)); x[9]  = tanh_fast(bf2f(w0 >> 16));
        x[10] = tanh_fast(bf2f(w1 & 0xFFFFu)); x[11] = tanh_fast(bf2f(w1 >> 16));
        x[12] = tanh_fast(bf2f(w2 & 0xFFFFu)); x[13] = tanh_fast(bf2f(w2 >> 16));
        x[14] = tanh_fast(bf2f(w3 & 0xFFFFu)); x[15] = tanh_fast(bf2f(w3 >> 16));
    }

    float out = 0.0f;
    #pragma unroll
    for (int ll = 0; ll < Lz; ll++) {
        const float* wf = fc_w + (size_t)ll * 1024 + lane * 8;
        const float* wr = wf + 512;
        float4 a0 = *(const float4*)wf;
        float4 a1 = *(const float4*)(wf + 4);
        float4 b0 = *(const float4*)wr;
        float4 b1 = *(const float4*)(wr + 4);
        float s = a0.x * x[0] + a0.y * x[1] + a0.z * x[2] + a0.w * x[3]
                + a1.x * x[4] + a1.y * x[5] + a1.z * x[6] + a1.w * x[7]
                + b0.x * x[8] + b0.y * x[9] + b0.z * x[10] + b0.w * x[11]
                + b1.x * x[12] + b1.y * x[13] + b1.z * x[14] + b1.w * x[15];
        #pragma unroll
        for (int off = 32; off; off >>= 1) s += __shfl_xor(s, off);
        if (lane == ll) out = s + fc_b[ll];
    }
    if (lane < Lz) feats[(size_t)m * Lz + lane] = out;
}

// ---------------- K4: CRF log_z + gold per batch ----------------
__global__ __launch_bounds__(64) void crf_kernel(const float* __restrict__ feats,
                                                 const float* __restrict__ trans,
                                                 const int* __restrict__ labels,
                                                 const int* __restrict__ lengths,
                                                 float* __restrict__ res) {
    const int b = blockIdx.x;
    const int lane = threadIdx.x;
    const int jj = (lane < Lz) ? lane : 0;

    float tcol[12];
    #pragma unroll
    for (int i = 0; i < 12; i++) tcol[i] = trans[i * Lz + jj];
    const int len = lengths[b];

    float alpha = 0.0f;
    for (int t = 0; t < Tz; t++) {
        float feat = feats[((size_t)b * Tz + t) * Lz + jj];
        float v[12];
        #pragma unroll
        for (int i = 0; i < 12; i++) v[i] = __shfl(alpha, i) + tcol[i];
        float m = v[0];
        #pragma unroll
        for (int i = 1; i < 12; i++) m = fmaxf(m, v[i]);
        float s = 0.0f;
        #pragma unroll
        for (int i = 0; i < 12; i++) s += __expf(v[i] - m);
        float newa = feat + m + __logf(s);
        if (t < len && lane < Lz) alpha = newa;
    }

    float val = (lane < Lz) ? (alpha + trans[jj * Lz + END_ID]) : -INFINITY;
    float m = val;
    #pragma unroll
    for (int off = 32; off; off >>= 1) m = fmaxf(m, __shfl_xor(m, off));
    float s = (lane < Lz) ? __expf(val - m) : 0.0f;
    #pragma unroll
    for (int off = 32; off; off >>= 1) s += __shfl_xor(s, off);
    float log_z = m + __logf(s);

    float g = 0.0f;
    for (int t = lane; t < Tz; t += 64) {
        if (t < len) {
            int nxt = labels[b * Tz + t];
            int prev = (t == 0) ? START_ID : labels[b * Tz + t - 1];
            g += feats[((size_t)b * Tz + t) * Lz + nxt] + trans[prev * Lz + nxt];
        }
    }
    #pragma unroll
    for (int off = 32; off; off >>= 1) g += __shfl_xor(g, off);
    int last = labels[b * Tz + len - 1];
    float gold = g + trans[last * Lz + END_ID];

    if (lane == 0) res[b] = log_z - gold;
}

// ---------------- K5: final reduce ----------------
__global__ __launch_bounds__(64) void reduce_kernel(const float* __restrict__ res,
                                                    float* __restrict__ out) {
    float v = res[threadIdx.x];
    #pragma unroll
    for (int off = 32; off; off >>= 1) v += __shfl_xor(v, off);
    if (threadIdx.x == 0) out[0] = v;
}

extern "C" void kernel_launch(void* const* d_in, const int* in_sizes, int n_in,
                              void* d_out, int out_size, void* d_ws, size_t ws_size,
                              hipStream_t stream) {
    const int*   sents     = (const int*)d_in[0];
    const int*   labels    = (const int*)d_in[1];
    const int*   lengths   = (const int*)d_in[2];
    const float* embedding = (const float*)d_in[3];
    const float* w_ih_f    = (const float*)d_in[4];
    const float* w_hh_f    = (const float*)d_in[5];
    const float* b_f       = (const float*)d_in[6];
    const float* w_ih_r    = (const float*)d_in[7];
    const float* w_hh_r    = (const float*)d_in[8];
    const float* b_r       = (const float*)d_in[9];
    const float* fc_w      = (const float*)d_in[10];
    const float* fc_b      = (const float*)d_in[11];
    const float* trans     = (const float*)d_in[12];
    (void)in_sizes; (void)n_in; (void)out_size; (void)ws_size;

    // Workspace (~102.8 MB)
    char* ws = (char*)d_ws;
    size_t off = 0;
    uint4*    emb_p = (uint4*)(ws + off);    off += (size_t)4 * 512 * 16 * 64 * 16;  // 33,554,432
    ushort16* hs    = (ushort16*)(ws + off); off += (size_t)2 * Bz * Tz * Hz * 2;    // 67,108,864
    float*    feats = (float*)(ws + off);    off += (size_t)Bz * Tz * Lz * 4;        //  1,572,864
    uint64*   h_ppT = (uint64*)(ws + off);   off += (size_t)2 * 2 * Bz * 256 * 8;    //    524,288
    float*    res   = (float*)(ws + off);    off += Bz * 4;

    prepack_kernel<<<8192, 256, 0, stream>>>(sents, embedding, emb_p);
    lstm_persist<<<128, 256, 0, stream>>>(w_ih_f, w_hh_f, b_f, w_ih_r, w_hh_r, b_r,
                                          emb_p, hs, h_ppT);
    feat_kernel<<<8192, 256, 0, stream>>>(hs, fc_w, fc_b, feats);
    crf_kernel<<<64, 64, 0, stream>>>(feats, trans, labels, lengths, res);
    reduce_kernel<<<1, 64, 0, stream>>>(res, (float*)d_out);
}

// Round 12
// 2057.749 us; speedup vs baseline: 1.3499x; 1.3499x over previous
//
#include <hip/hip_runtime.h>
#include <stdint.h>

#define Bz 64
#define Tz 512
#define Ez 512
#define Hz 512
#define Lz 12
#define START_ID 10
#define END_ID 11

typedef unsigned int uint32;
typedef unsigned long long uint64;
typedef unsigned short ushort16;
typedef __bf16 bf16x8 __attribute__((ext_vector_type(8)));
typedef float f32x4 __attribute__((ext_vector_type(4)));

__device__ __forceinline__ float bf2f(uint32 u) {
    return __uint_as_float(u << 16);
}
__device__ __forceinline__ ushort16 f2bf(float f) {
    uint32 x = __float_as_uint(f);
    x += 0x7FFFu + ((x >> 16) & 1u);
    return (ushort16)(x >> 16);
}
__device__ __forceinline__ float sigf(float x) {
    return 1.0f / (1.0f + __expf(-x));
}
__device__ __forceinline__ float tanh_fast(float x) {
    return 1.0f - 2.0f / (__expf(2.0f * x) + 1.0f);
}
__device__ __forceinline__ bf16x8 packbf8(float4 a, float4 b) {
    union { ushort16 u[8]; bf16x8 v; } r;
    r.u[0] = f2bf(a.x); r.u[1] = f2bf(a.y); r.u[2] = f2bf(a.z); r.u[3] = f2bf(a.w);
    r.u[4] = f2bf(b.x); r.u[5] = f2bf(b.y); r.u[6] = f2bf(b.z); r.u[7] = f2bf(b.w);
    return r.v;
}

// ---- K0: pack embeds into A-fragment order: emb_p[((bg*512+t)*16+kst)*64 + lane] = 16B ----
// lane l supplies A[row = bg*16 + (l&15)][k = kst*32 + (l>>4)*8 + i], i=0..7
__global__ __launch_bounds__(256) void prepack_kernel(const int* __restrict__ sents,
                                                      const float* __restrict__ emb,
                                                      uint4* __restrict__ emb_p) {
    int c = blockIdx.x * 256 + threadIdx.x;      // 0 .. 2^21-1
    int l   = c & 63;
    int kst = (c >> 6) & 15;
    int t   = (c >> 10) & 511;
    int bg  = c >> 19;
    int b   = (bg << 4) + (l & 15);
    int e0  = (kst << 5) + ((l >> 4) << 3);
    const float* p = emb + (size_t)sents[b * Tz + t] * Ez + e0;
    float4 f0 = *(const float4*)p;
    float4 f1 = *(const float4*)(p + 4);
    uint32 r0 = (uint32)f2bf(f0.x) | ((uint32)f2bf(f0.y) << 16);
    uint32 r1 = (uint32)f2bf(f0.z) | ((uint32)f2bf(f0.w) << 16);
    uint32 r2 = (uint32)f2bf(f1.x) | ((uint32)f2bf(f1.y) << 16);
    uint32 r3 = (uint32)f2bf(f1.z) | ((uint32)f2bf(f1.w) << 16);
    emb_p[c] = make_uint4(r0, r1, r2, r3);
}

// ---- K1: persistent BiLSTM. 128 blocks = 8 groups (2 dir x 4 bgroup of 16 batch) x 16 ugroups(32 units).
// R8 protocol (measured optimum of 6 exchange protocols): per-thread publish store ->
// vmcnt(0) ack -> syncthreads -> one flag/block; consumers poll 16 flags with 16 lanes
// (tight spin, >= compare, guarded), then bulk-load h. x-GEMM after h-GEMM so xf
// prefetch loads get the poll window to land. Own h-slice forwarded via LDS h_stage.
__global__ __launch_bounds__(256, 1) void lstm_persist(
    const float* __restrict__ w_ih_f, const float* __restrict__ w_hh_f, const float* __restrict__ b_f,
    const float* __restrict__ w_ih_r, const float* __restrict__ w_hh_r, const float* __restrict__ b_r,
    const uint4* __restrict__ emb_p,
    ushort16* __restrict__ hs,          // [2][64][512][512] bf16
    uint32* __restrict__ h_pp,          // [2 parity][2 dir][64][256 words] (2 units/word)
    uint32* __restrict__ bar)           // 128 slots x 32-uint stride (128 B apart)
{
    const int bid = blockIdx.x;
    const int grp = bid & 7;
    const int d   = grp >> 2;
    const int bg  = grp & 3;
    const int ug  = bid >> 3;            // 0..15
    const int tid = threadIdx.x;
    const int w   = tid >> 6;            // wave = gate type
    const int l   = tid & 63;

    __shared__ __align__(16) char h_lds[16384];      // [16 b][512 k] bf16, XOR-swizzled
    __shared__ float gx[2048];                       // [16 b][4 gate][32 u] f32
    __shared__ uint32 h_stage[256];                  // own-block h slice (2 units/word)

    const float* Whh  = d ? w_hh_r : w_hh_f;
    const float* Wih  = d ? w_ih_r : w_ih_f;
    const float* bias = d ? b_r : b_f;
    const int u0 = ug << 5;

    // ---- load B-fragments into registers (two 16-col halves nn=0,1) ----
    bf16x8 Bih[2][16], Bhh[2][16];
    #pragma unroll
    for (int nn = 0; nn < 2; nn++) {
        const int wrow = (w << 9) + u0 + (nn << 4) + (l & 15);
        const int koff = (l >> 4) << 3;
        #pragma unroll
        for (int kst = 0; kst < 16; kst++) {
            const float* p = Wih + (size_t)wrow * Ez + (kst << 5) + koff;
            Bih[nn][kst] = packbf8(*(const float4*)p, *(const float4*)(p + 4));
            const float* q = Whh + (size_t)wrow * Hz + (kst << 5) + koff;
            Bhh[nn][kst] = packbf8(*(const float4*)q, *(const float4*)(q + 4));
        }
    }

    // activation thread mapping: b = tid>>4 (0..15 local), uw = tid&15 -> units 2uw,2uw+1
    const int ab = tid >> 4;
    const int uw = tid & 15;
    const float bi0  = bias[u0 + 2*uw],        bi1  = bias[u0 + 2*uw + 1];
    const float bf0  = bias[512 + u0 + 2*uw],  bf1  = bias[512 + u0 + 2*uw + 1];
    const float bg0  = bias[1024 + u0 + 2*uw], bg1  = bias[1024 + u0 + 2*uw + 1];
    const float bo0  = bias[1536 + u0 + 2*uw], bo1  = bias[1536 + u0 + 2*uw + 1];
    float c0 = 0.0f, c1 = 0.0f;

    const int r16 = tid >> 4, seg = tid & 15;
    uint32* slot = bar + (((grp << 4) + ug) << 5);
    const uint64* h_pp64 = (const uint64*)h_pp;
    const uint4* xbase = emb_p + (((size_t)bg << 9) << 10);

    // preload x fragments for t=0
    uint4 xf[16];
    {
        const uint4* xb = xbase + ((size_t)(d ? (Tz - 1) : 0) << 10) + l;
        #pragma unroll
        for (int kst = 0; kst < 16; kst++) xf[kst] = xb[(size_t)kst << 6];
    }

    for (int t = 0; t < Tz; t++) {
        const int tg = d ? (Tz - 1 - t) : t;

        f32x4 acc0[2], acc1[2];
        #pragma unroll
        for (int i = 0; i < 2; i++) {
            acc0[i] = (f32x4){0.f, 0.f, 0.f, 0.f};
            acc1[i] = (f32x4){0.f, 0.f, 0.f, 0.f};
        }

        if (t > 0) {
            // ---- poll 16 producer flags with 16 lanes (wave 0), tight spin ----
            if (tid < 64) {
                const uint32 tgt = (uint32)t;
                uint32* sl = bar + (((grp << 4) + (l & 15)) << 5);
                int guard = 0;
                for (;;) {
                    uint32 v = tgt;
                    if (l < 16) v = __hip_atomic_load(sl, __ATOMIC_RELAXED, __HIP_MEMORY_SCOPE_AGENT);
                    if (__all((int)(v >= tgt))) break;
                    if (++guard > (1 << 14)) break;    // anti-hang insurance
                }
            }
            __syncthreads();

            // ---- load h(t-1): remote slices from MALL, own slice from LDS h_stage ----
            uint64 hv8[8];
            const uint64* hp = h_pp64 + ((size_t)((((t - 1) & 1) << 1) + d) * 64 + (bg << 4) + r16) * 128;
            if (seg != ug) {
                #pragma unroll
                for (int jj = 0; jj < 8; jj++)
                    hv8[jj] = __hip_atomic_load(hp + (seg << 3) + jj, __ATOMIC_RELAXED, __HIP_MEMORY_SCOPE_AGENT);
            } else {
                #pragma unroll
                for (int jj = 0; jj < 8; jj++)
                    hv8[jj] = (uint64)h_stage[(r16 << 4) + (jj << 1)]
                            | ((uint64)h_stage[(r16 << 4) + (jj << 1) + 1] << 32);
            }
            #pragma unroll
            for (int jj = 0; jj < 8; jj++) {
                const int idx8 = (seg << 3) + jj;
                *(uint64*)(h_lds + (r16 << 10) + ((((idx8 >> 1) << 4) ^ (r16 << 4))) + ((idx8 & 1) << 3)) = hv8[jj];
            }
            __syncthreads();

            // ---- h-GEMM ----
            #pragma unroll
            for (int kst = 0; kst < 16; kst++) {
                bf16x8 a = *(const bf16x8*)(h_lds + ((l & 15) << 10) +
                            (((kst << 6) + ((l >> 4) << 4)) ^ ((l & 15) << 4)));
                acc0[kst & 1] = __builtin_amdgcn_mfma_f32_16x16x32_bf16(a, Bhh[0][kst], acc0[kst & 1], 0, 0, 0);
                acc1[kst & 1] = __builtin_amdgcn_mfma_f32_16x16x32_bf16(a, Bhh[1][kst], acc1[kst & 1], 0, 0, 0);
            }
        }

        // ---- x-GEMM (after h-GEMM: xf prefetch loads had poll+hload+hGEMM to complete) ----
        #pragma unroll
        for (int kst = 0; kst < 16; kst++) {
            union { uint4 q; bf16x8 v; } x;
            x.q = xf[kst];
            acc0[kst & 1] = __builtin_amdgcn_mfma_f32_16x16x32_bf16(x.v, Bih[0][kst], acc0[kst & 1], 0, 0, 0);
            acc1[kst & 1] = __builtin_amdgcn_mfma_f32_16x16x32_bf16(x.v, Bih[1][kst], acc1[kst & 1], 0, 0, 0);
        }

        f32x4 g0 = acc0[0] + acc0[1];
        f32x4 g1 = acc1[0] + acc1[1];

        // ---- gate exchange: D[row=(l>>4)*4+r][col=l&15] -> gx[b][gate][u] ----
        #pragma unroll
        for (int r = 0; r < 4; r++) {
            const int b = ((l >> 4) << 2) + r;
            gx[(b << 7) + (w << 5) + (l & 15)] = g0[r];
            gx[(b << 7) + (w << 5) + 16 + (l & 15)] = g1[r];
        }
        __syncthreads();

        // ---- activation + publish (2 units per thread) ----
        uint32 hval;
        {
            const int base = (ab << 7) + (uw << 1);
            float gi_0 = gx[base],      gi_1 = gx[base + 1];
            float gf_0 = gx[base + 32], gf_1 = gx[base + 33];
            float gg_0 = gx[base + 64], gg_1 = gx[base + 65];
            float go_0 = gx[base + 96], go_1 = gx[base + 97];
            c0 = sigf(gf_0 + bf0) * c0 + sigf(gi_0 + bi0) * tanh_fast(gg_0 + bg0);
            float hn0 = sigf(go_0 + bo0) * tanh_fast(c0);
            c1 = sigf(gf_1 + bf1) * c1 + sigf(gi_1 + bi1) * tanh_fast(gg_1 + bg1);
            float hn1 = sigf(go_1 + bo1) * tanh_fast(c1);
            hval = (uint32)f2bf(hn0) | ((uint32)f2bf(hn1) << 16);
            h_stage[(ab << 4) + uw] = hval;
            const size_t pidx = ((size_t)(((t & 1) << 1) + d) * 64 + (bg << 4) + ab) * 256 + (ug << 4) + uw;
            __hip_atomic_store(h_pp + pidx, hval, __ATOMIC_RELAXED, __HIP_MEMORY_SCOPE_AGENT);
        }
        asm volatile("s_waitcnt vmcnt(0)" ::: "memory");   // publish stores globally visible
        __syncthreads();
        if (tid == 0)
            __hip_atomic_store(slot, (uint32)(t + 1), __ATOMIC_RELAXED, __HIP_MEMORY_SCOPE_AGENT);

        // ---- off critical path: hs output + x prefetch for t+1 ----
        {
            const size_t hrow = (((size_t)(d << 6) + (bg << 4) + ab) * 512 + tg) * 512 + u0 + (uw << 1);
            *(uint32*)(hs + hrow) = hval;
        }
        if (t < Tz - 1) {
            const int tg2 = d ? (Tz - 2 - t) : (t + 1);
            const uint4* xb = xbase + ((size_t)tg2 << 10) + l;
            #pragma unroll
            for (int kst = 0; kst < 16; kst++) xf[kst] = xb[(size_t)kst << 6];
        }
    }
}

// ---------------- K3: feats = tanh(concat(hf,hr)) @ fc_w^T + fc_b ----------------
__global__ __launch_bounds__(256) void feat_kernel(const ushort16* __restrict__ hs,
                                                   const float* __restrict__ fc_w,
                                                   const float* __restrict__ fc_b,
                                                   float* __restrict__ feats) {
    const int m = blockIdx.x * 4 + (threadIdx.x >> 6);   // row (b*T+t)
    const int lane = threadIdx.x & 63;

    const ushort16* hf = hs + (size_t)m * Hz + lane * 8;
    const ushort16* hr = hs + (size_t)Bz * Tz * Hz + (size_t)m * Hz + lane * 8;
    uint4 vf = *(const uint4*)hf;
    uint4 vr = *(const uint4*)hr;

    float x[16];
    {
        uint32 w0 = vf.x, w1 = vf.y, w2 = vf.z, w3 = vf.w;
        x[0] = tanh_fast(bf2f(w0 & 0xFFFFu)); x[1] = tanh_fast(bf2f(w0 >> 16));
        x[2] = tanh_fast(bf2f(w1 & 0xFFFFu)); x[3] = tanh_fast(bf2f(w1 >> 16));
        x[4] = tanh_fast(bf2f(w2 & 0xFFFFu)); x[5] = tanh_fast(bf2f(w2 >> 16));
        x[6] = tanh_fast(bf2f(w3 & 0xFFFFu)); x[7] = tanh_fast(bf2f(w3 >> 16));
        w0 = vr.x; w1 = vr.y; w2 = vr.z; w3 = vr.w;
        x[8]  = tanh_fast(bf2f(w0 & 0xFFFFu)); x[9]  = tanh_fast(bf2f(w0 >> 16));
        x[10] = tanh_fast(bf2f(w1 & 0xFFFFu)); x[11] = tanh_fast(bf2f(w1 >> 16));
        x[12] = tanh_fast(bf2f(w2 & 0xFFFFu)); x[13] = tanh_fast(bf2f(w2 >> 16));
        x[14] = tanh_fast(bf2f(w3 & 0xFFFFu)); x[15] = tanh_fast(bf2f(w3 >> 16));
    }

    float out = 0.0f;
    #pragma unroll
    for (int ll = 0; ll < Lz; ll++) {
        const float* wf = fc_w + (size_t)ll * 1024 + lane * 8;
        const float* wr = wf + 512;
        float4 a0 = *(const float4*)wf;
        float4 a1 = *(const float4*)(wf + 4);
        float4 b0 = *(const float4*)wr;
        float4 b1 = *(const float4*)(wr + 4);
        float s = a0.x * x[0] + a0.y * x[1] + a0.z * x[2] + a0.w * x[3]
                + a1.x * x[4] + a1.y * x[5] + a1.z * x[6] + a1.w * x[7]
                + b0.x * x[8] + b0.y * x[9] + b0.z * x[10] + b0.w * x[11]
                + b1.x * x[12] + b1.y * x[13] + b1.z * x[14] + b1.w * x[15];
        #pragma unroll
        for (int off = 32; off; off >>= 1) s += __shfl_xor(s, off);
        if (lane == ll) out = s + fc_b[ll];
    }
    if (lane < Lz) feats[(size_t)m * Lz + lane] = out;
}

// ---------------- K4: CRF log_z + gold per batch ----------------
__global__ __launch_bounds__(64) void crf_kernel(const float* __restrict__ feats,
                                                 const float* __restrict__ trans,
                                                 const int* __restrict__ labels,
                                                 const int* __restrict__ lengths,
                                                 float* __restrict__ res) {
    const int b = blockIdx.x;
    const int lane = threadIdx.x;
    const int jj = (lane < Lz) ? lane : 0;

    float tcol[12];
    #pragma unroll
    for (int i = 0; i < 12; i++) tcol[i] = trans[i * Lz + jj];
    const int len = lengths[b];

    float alpha = 0.0f;
    for (int t = 0; t < Tz; t++) {
        float feat = feats[((size_t)b * Tz + t) * Lz + jj];
        float v[12];
        #pragma unroll
        for (int i = 0; i < 12; i++) v[i] = __shfl(alpha, i) + tcol[i];
        float m = v[0];
        #pragma unroll
        for (int i = 1; i < 12; i++) m = fmaxf(m, v[i]);
        float s = 0.0f;
        #pragma unroll
        for (int i = 0; i < 12; i++) s += __expf(v[i] - m);
        float newa = feat + m + __logf(s);
        if (t < len && lane < Lz) alpha = newa;
    }

    float val = (lane < Lz) ? (alpha + trans[jj * Lz + END_ID]) : -INFINITY;
    float m = val;
    #pragma unroll
    for (int off = 32; off; off >>= 1) m = fmaxf(m, __shfl_xor(m, off));
    float s = (lane < Lz) ? __expf(val - m) : 0.0f;
    #pragma unroll
    for (int off = 32; off; off >>= 1) s += __shfl_xor(s, off);
    float log_z = m + __logf(s);

    float g = 0.0f;
    for (int t = lane; t < Tz; t += 64) {
        if (t < len) {
            int nxt = labels[b * Tz + t];
            int prev = (t == 0) ? START_ID : labels[b * Tz + t - 1];
            g += feats[((size_t)b * Tz + t) * Lz + nxt] + trans[prev * Lz + nxt];
        }
    }
    #pragma unroll
    for (int off = 32; off; off >>= 1) g += __shfl_xor(g, off);
    int last = labels[b * Tz + len - 1];
    float gold = g + trans[last * Lz + END_ID];

    if (lane == 0) res[b] = log_z - gold;
}

// ---------------- K5: final reduce ----------------
__global__ __launch_bounds__(64) void reduce_kernel(const float* __restrict__ res,
                                                    float* __restrict__ out) {
    float v = res[threadIdx.x];
    #pragma unroll
    for (int off = 32; off; off >>= 1) v += __shfl_xor(v, off);
    if (threadIdx.x == 0) out[0] = v;
}

extern "C" void kernel_launch(void* const* d_in, const int* in_sizes, int n_in,
                              void* d_out, int out_size, void* d_ws, size_t ws_size,
                              hipStream_t stream) {
    const int*   sents     = (const int*)d_in[0];
    const int*   labels    = (const int*)d_in[1];
    const int*   lengths   = (const int*)d_in[2];
    const float* embedding = (const float*)d_in[3];
    const float* w_ih_f    = (const float*)d_in[4];
    const float* w_hh_f    = (const float*)d_in[5];
    const float* b_f       = (const float*)d_in[6];
    const float* w_ih_r    = (const float*)d_in[7];
    const float* w_hh_r    = (const float*)d_in[8];
    const float* b_r       = (const float*)d_in[9];
    const float* fc_w      = (const float*)d_in[10];
    const float* fc_b      = (const float*)d_in[11];
    const float* trans     = (const float*)d_in[12];
    (void)in_sizes; (void)n_in; (void)out_size; (void)ws_size;

    // Workspace (~102.5 MB)
    char* ws = (char*)d_ws;
    size_t off = 0;
    uint4*    emb_p = (uint4*)(ws + off);    off += (size_t)4 * 512 * 16 * 64 * 16;  // 33,554,432
    ushort16* hs    = (ushort16*)(ws + off); off += (size_t)2 * Bz * Tz * Hz * 2;    // 67,108,864
    float*    feats = (float*)(ws + off);    off += (size_t)Bz * Tz * Lz * 4;        //  1,572,864
    uint32*   h_pp  = (uint32*)(ws + off);   off += (size_t)2 * 2 * Bz * 256 * 4;    //    262,144
    uint32*   bar   = (uint32*)(ws + off);   off += 16384;
    float*    res   = (float*)(ws + off);    off += Bz * 4;

    hipMemsetAsync(bar, 0, 16384, stream);
    prepack_kernel<<<8192, 256, 0, stream>>>(sents, embedding, emb_p);
    lstm_persist<<<128, 256, 0, stream>>>(w_ih_f, w_hh_f, b_f, w_ih_r, w_hh_r, b_r,
                                          emb_p, hs, h_pp, bar);
    feat_kernel<<<8192, 256, 0, stream>>>(hs, fc_w, fc_b, feats);
    crf_kernel<<<64, 64, 0, stream>>>(feats, trans, labels, lengths, res);
    reduce_kernel<<<1, 64, 0, stream>>>(res, (float*)d_out);
}